// Round 6
// baseline (52.071 us; speedup 1.0000x reference)
//
#include <hip/hip_runtime.h>
#include <hip/hip_bf16.h>

#define KC 262144

typedef __attribute__((ext_vector_type(8))) short bf16x8;
typedef __attribute__((ext_vector_type(4))) float f32x4;
typedef unsigned short u16;
typedef unsigned int u32;

__device__ __forceinline__ u16 f2bf(float f) {
    u32 u = __float_as_uint(f);
    return (u16)((u + 0x7fffu + ((u >> 16) & 1u)) >> 16);   // RNE, finite vals
}
__device__ __forceinline__ u32 pk2(float a, float b) {
    return (u32)f2bf(a) | ((u32)f2bf(b) << 16);
}
__device__ __forceinline__ float bf2f(u32 h) {
    return __uint_as_float(h << 16);
}

// ---------------------------------------------------------------------------
// Prep: stacked bf16 weights in ws (bias via ones-row at k==80 for L2/L3).
//   W1s u16[80][64]   rows 0..39 = W_o1, 40..79 = W_t1
//   W2s u16[80][96]   block-diag W_o2/W_t2, col 80 = bias
//   W3s u16[16][96]   rows 0..8 = W_o3 | 9..11 = W_t3 (cols 40..79) | 12..15=0
//   b1s f32[80]       [b_o1 ; b_t1]
// ---------------------------------------------------------------------------
__global__ __launch_bounds__(256) void prep(
    const float* __restrict__ Wo1, const float* __restrict__ bo1,
    const float* __restrict__ Wo2, const float* __restrict__ bo2,
    const float* __restrict__ Wo3, const float* __restrict__ bo3,
    const float* __restrict__ Wt1, const float* __restrict__ bt1,
    const float* __restrict__ Wt2, const float* __restrict__ bt2,
    const float* __restrict__ Wt3, const float* __restrict__ bt3,
    u16* __restrict__ ws)
{
    u16* W1s = ws;                      // 5120 u16
    u16* W2s = ws + 5120;               // 7680 u16
    u16* W3s = ws + 12800;              // 1536 u16
    float* b1s = (float*)(ws + 14336);  // 80 f32
    const int t0 = blockIdx.x * 256 + threadIdx.x;
    const int NT = gridDim.x * 256;

    for (int i = t0; i < 5120; i += NT) {
        int r = i >> 6, k = i & 63;
        float v = (r < 40) ? Wo1[r * 64 + k] : Wt1[(r - 40) * 64 + k];
        W1s[i] = f2bf(v);
    }
    for (int i = t0; i < 7680; i += NT) {
        int r = i / 96, k = i - r * 96;
        float v = 0.f;
        if (r < 40) {
            if (k < 40) v = Wo2[r * 40 + k];
            else if (k == 80) v = bo2[r];
        } else {
            int rr = r - 40;
            if (k >= 40 && k < 80) v = Wt2[rr * 40 + (k - 40)];
            else if (k == 80) v = bt2[rr];
        }
        W2s[i] = f2bf(v);
    }
    for (int i = t0; i < 1536; i += NT) {
        int r = i / 96, k = i - r * 96;
        float v = 0.f;
        if (r < 9) {
            if (k < 40) v = Wo3[r * 40 + k];
            else if (k == 80) v = bo3[r];
        } else if (r < 12) {
            int rr = r - 9;
            if (k >= 40 && k < 80) v = Wt3[rr * 40 + (k - 40)];
            else if (k == 80) v = bt3[rr];
        }
        W3s[i] = f2bf(v);
    }
    for (int i = t0; i < 80; i += NT)
        b1s[i] = (i < 40) ? bo1[i] : bt1[i - 40];
}

// ---------------------------------------------------------------------------
// Main: one wave = 64 columns (4 tiles of 16). 4096 waves, 1024 blocks ->
// 4 blocks/CU, 4 waves/SIMD (TLP doubles vs r5). hst stride 120 u16:
// base banks 28c mod 32 tile perfectly -> 2-way max (free). Block-diag zero
// A2 frags (m>=3,s=0) skipped.
// ---------------------------------------------------------------------------
__global__ __launch_bounds__(256, 4) void mlp_mfma(
    const float* __restrict__ x, const u16* __restrict__ ws,
    float* __restrict__ out)
{
    const u16* W1s = ws;
    const u16* W2s = ws + 5120;
    const u16* W3s = ws + 12800;
    const float* b1s = (const float*)(ws + 14336);

    __shared__ u16 hst[4][16][120];   // [wave][col][row(96 used)]
    __shared__ u16 l3s[4][64][16];    // [wave][col][row]

    const int tid = threadIdx.x;
    const int wid = tid >> 6;
    const int lane = tid & 63;
    const int g = lane >> 4;
    const int c = lane & 15;
    const int wgid = blockIdx.x * 4 + wid;   // 0..4095
    const int cbase = wgid * 64;

    // ---- A-fragments (weights) ----
    bf16x8 A1[5][2], A3[3];
    f32x4 b1v[5];
#pragma unroll
    for (int m = 0; m < 5; ++m) {
#pragma unroll
        for (int s = 0; s < 2; ++s)
            A1[m][s] = *(const bf16x8*)(W1s + (16 * m + c) * 64 + 32 * s + 8 * g);
        b1v[m] = *(const f32x4*)(b1s + 16 * m + 4 * g);
    }
    bf16x8 A2[5][3];
#pragma unroll
    for (int m = 0; m < 5; ++m)
#pragma unroll
        for (int s = 0; s < 3; ++s)
            if (!(s == 0 && m >= 3))
                A2[m][s] = *(const bf16x8*)(W2s + (16 * m + c) * 96 + 32 * s + 8 * g);
#pragma unroll
    for (int s = 0; s < 3; ++s)
        A3[s] = *(const bf16x8*)(W3s + c * 96 + 32 * s + 8 * g);

    // ---- hst pad rows 80..95: row 80 = 1.0 (bias row), rest 0 ----
    {
        uint2 z;
        z.x = (g == 0) ? 0x00003f80u : 0u;
        z.y = 0u;
        *(uint2*)&hst[wid][c][80 + 4 * g] = z;
    }

    // ---- per-lane x byte offsets (B-frag pattern) ----
    u32 xoff[16];
#pragma unroll
    for (int jj = 0; jj < 16; ++jj) {
        int row = 8 * g + (jj & 7) + 32 * (jj >> 3);
        xoff[jj] = (u32)((row * KC + cbase + c) * 4);
    }
    const char* xb_ = (const char*)x;

#pragma unroll
    for (int t = 0; t < 4; ++t) {
        float xr[16];
#pragma unroll
        for (int jj = 0; jj < 16; ++jj)
            xr[jj] = *(const float*)(xb_ + (xoff[jj] + t * 64));
        bf16x8 xv[2];
#pragma unroll
        for (int s = 0; s < 2; ++s) {
            union { u32 u[4]; bf16x8 v; } uu;
#pragma unroll
            for (int p = 0; p < 4; ++p)
                uu.u[p] = pk2(xr[8 * s + 2 * p], xr[8 * s + 2 * p + 1]);
            xv[s] = uu.v;
        }

        // ---- L1 ----
        f32x4 a1[5];
#pragma unroll
        for (int m = 0; m < 5; ++m) a1[m] = b1v[m];
#pragma unroll
        for (int s = 0; s < 2; ++s)
#pragma unroll
            for (int m = 0; m < 5; ++m)
                a1[m] = __builtin_amdgcn_mfma_f32_16x16x32_bf16(
                    A1[m][s], xv[s], a1[m], 0, 0, 0);
#pragma unroll
        for (int m = 0; m < 5; ++m) {
            uint2 w;
            w.x = pk2(fmaxf(a1[m][0], 0.f), fmaxf(a1[m][1], 0.f));
            w.y = pk2(fmaxf(a1[m][2], 0.f), fmaxf(a1[m][3], 0.f));
            *(uint2*)&hst[wid][c][16 * m + 4 * g] = w;
        }

        // ---- L2 (K=96; skip zero block-diag frags m>=3,s=0) ----
        f32x4 a2[5];
#pragma unroll
        for (int m = 0; m < 5; ++m) a2[m] = f32x4{0.f, 0.f, 0.f, 0.f};
#pragma unroll
        for (int s = 0; s < 3; ++s) {
            bf16x8 hb = *(const bf16x8*)&hst[wid][c][32 * s + 8 * g];
#pragma unroll
            for (int m = 0; m < 5; ++m)
                if (!(s == 0 && m >= 3))
                    a2[m] = __builtin_amdgcn_mfma_f32_16x16x32_bf16(
                        A2[m][s], hb, a2[m], 0, 0, 0);
        }
#pragma unroll
        for (int m = 0; m < 5; ++m) {
            uint2 w;
            w.x = pk2(fmaxf(a2[m][0], 0.f), fmaxf(a2[m][1], 0.f));
            w.y = pk2(fmaxf(a2[m][2], 0.f), fmaxf(a2[m][3], 0.f));
            *(uint2*)&hst[wid][c][16 * m + 4 * g] = w;
        }

        // ---- L3 ----
        f32x4 a3 = f32x4{0.f, 0.f, 0.f, 0.f};
#pragma unroll
        for (int s = 0; s < 3; ++s) {
            bf16x8 hb = *(const bf16x8*)&hst[wid][c][32 * s + 8 * g];
            a3 = __builtin_amdgcn_mfma_f32_16x16x32_bf16(
                A3[s], hb, a3, 0, 0, 0);
        }
        {
            uint2 w;
            w.x = pk2(fmaxf(a3[0], 0.f), fmaxf(a3[1], 0.f));
            w.y = pk2(fmaxf(a3[2], 0.f), fmaxf(a3[3], 0.f));
            *(uint2*)&l3s[wid][16 * t + c][4 * g] = w;
        }
    }

    // ---- per-column phase: lane <-> column cbase+lane ----
    {
        uint4 q0 = *(const uint4*)&l3s[wid][lane][0];
        uint4 q1 = *(const uint4*)&l3s[wid][lane][8];
        float om[9];
        om[0] = bf2f(q0.x & 0xffffu); om[1] = bf2f(q0.x >> 16);
        om[2] = bf2f(q0.y & 0xffffu); om[3] = bf2f(q0.y >> 16);
        om[4] = bf2f(q0.z & 0xffffu); om[5] = bf2f(q0.z >> 16);
        om[6] = bf2f(q0.w & 0xffffu); om[7] = bf2f(q0.w >> 16);
        om[8] = bf2f(q1.x & 0xffffu);
        float tr0 = bf2f(q1.x >> 16);
        float tr1 = bf2f(q1.y & 0xffffu);
        float tr2 = bf2f(q1.y >> 16);

        const size_t ob = (size_t)cbase + lane;
#pragma unroll
        for (int j = 0; j < 9; ++j)
            out[(size_t)j * KC + ob] = om[j];
        out[(size_t)18 * KC + ob] = tr0;
        out[(size_t)19 * KC + ob] = tr1;
        out[(size_t)20 * KC + ob] = tr2;

        // expm: scale 1/32, Taylor-9 Horner, 5 squarings
        float B[9];
#pragma unroll
        for (int i = 0; i < 9; ++i) B[i] = om[i] * (1.0f / 32.0f);
        float T[9] = {1.f, 0.f, 0.f, 0.f, 1.f, 0.f, 0.f, 0.f, 1.f};
#pragma unroll
        for (int m = 9; m >= 1; --m) {
            float U[9];
#pragma unroll
            for (int rr = 0; rr < 3; ++rr)
#pragma unroll
                for (int cc = 0; cc < 3; ++cc)
                    U[rr * 3 + cc] = B[rr * 3 + 0] * T[0 * 3 + cc]
                                   + B[rr * 3 + 1] * T[1 * 3 + cc]
                                   + B[rr * 3 + 2] * T[2 * 3 + cc];
            const float s = 1.0f / (float)m;
#pragma unroll
            for (int i = 0; i < 9; ++i)
                T[i] = U[i] * s + ((i == 0 || i == 4 || i == 8) ? 1.0f : 0.0f);
        }
#pragma unroll
        for (int q = 0; q < 5; ++q) {
            float U[9];
#pragma unroll
            for (int rr = 0; rr < 3; ++rr)
#pragma unroll
                for (int cc = 0; cc < 3; ++cc)
                    U[rr * 3 + cc] = T[rr * 3 + 0] * T[0 * 3 + cc]
                                   + T[rr * 3 + 1] * T[1 * 3 + cc]
                                   + T[rr * 3 + 2] * T[2 * 3 + cc];
#pragma unroll
            for (int i = 0; i < 9; ++i) T[i] = U[i];
        }
#pragma unroll
        for (int j = 0; j < 9; ++j)
            out[(size_t)(9 + j) * KC + ob] = T[j];
    }
}

extern "C" void kernel_launch(void* const* d_in, const int* in_sizes, int n_in,
                              void* d_out, int out_size, void* d_ws, size_t ws_size,
                              hipStream_t stream) {
    const float* x   = (const float*)d_in[0];
    const float* Wo1 = (const float*)d_in[1];
    const float* bo1 = (const float*)d_in[2];
    const float* Wo2 = (const float*)d_in[3];
    const float* bo2 = (const float*)d_in[4];
    const float* Wo3 = (const float*)d_in[5];
    const float* bo3 = (const float*)d_in[6];
    const float* Wt1 = (const float*)d_in[7];
    const float* bt1 = (const float*)d_in[8];
    const float* Wt2 = (const float*)d_in[9];
    const float* bt2 = (const float*)d_in[10];
    const float* Wt3 = (const float*)d_in[11];
    const float* bt3 = (const float*)d_in[12];

    u16* ws = (u16*)d_ws;
    float* out = (float*)d_out;

    hipLaunchKernelGGL(prep, dim3(16), dim3(256), 0, stream,
                       Wo1, bo1, Wo2, bo2, Wo3, bo3,
                       Wt1, bt1, Wt2, bt2, Wt3, bt3, ws);
    hipLaunchKernelGGL(mlp_mfma, dim3(1024), dim3(256), 0, stream,
                       x, ws, out);
}

// Round 7
// 34.409 us; speedup vs baseline: 1.5133x; 1.5133x over previous
//
#include <hip/hip_runtime.h>
#include <hip/hip_bf16.h>

#define KC 262144

typedef __attribute__((ext_vector_type(8))) short bf16x8;
typedef __attribute__((ext_vector_type(4))) float f32x4;
typedef unsigned short u16;
typedef unsigned int u32;

__device__ __forceinline__ u16 f2bf(float f) {
    u32 u = __float_as_uint(f);
    return (u16)((u + 0x7fffu + ((u >> 16) & 1u)) >> 16);   // RNE, finite vals
}
__device__ __forceinline__ u32 pk2(float a, float b) {
    return (u32)f2bf(a) | ((u32)f2bf(b) << 16);
}
__device__ __forceinline__ float bf2f(u32 h) {
    return __uint_as_float(h << 16);
}

// ---------------------------------------------------------------------------
// Prep: stacked bf16 weights in ws (bias via ones-row at k==80 for L2/L3).
//   W1s u16[80][64]   rows 0..39 = W_o1, 40..79 = W_t1
//   W2s u16[80][96]   block-diag W_o2/W_t2, col 80 = bias
//   W3s u16[16][96]   rows 0..8 = W_o3 | 9..11 = W_t3 (cols 40..79) | 12..15=0
//   b1s f32[80]       [b_o1 ; b_t1]
// ---------------------------------------------------------------------------
__global__ __launch_bounds__(256) void prep(
    const float* __restrict__ Wo1, const float* __restrict__ bo1,
    const float* __restrict__ Wo2, const float* __restrict__ bo2,
    const float* __restrict__ Wo3, const float* __restrict__ bo3,
    const float* __restrict__ Wt1, const float* __restrict__ bt1,
    const float* __restrict__ Wt2, const float* __restrict__ bt2,
    const float* __restrict__ Wt3, const float* __restrict__ bt3,
    u16* __restrict__ ws)
{
    u16* W1s = ws;                      // 5120 u16
    u16* W2s = ws + 5120;               // 7680 u16
    u16* W3s = ws + 12800;              // 1536 u16
    float* b1s = (float*)(ws + 14336);  // 80 f32
    const int t0 = blockIdx.x * 256 + threadIdx.x;
    const int NT = gridDim.x * 256;

    for (int i = t0; i < 5120; i += NT) {
        int r = i >> 6, k = i & 63;
        float v = (r < 40) ? Wo1[r * 64 + k] : Wt1[(r - 40) * 64 + k];
        W1s[i] = f2bf(v);
    }
    for (int i = t0; i < 7680; i += NT) {
        int r = i / 96, k = i - r * 96;
        float v = 0.f;
        if (r < 40) {
            if (k < 40) v = Wo2[r * 40 + k];
            else if (k == 80) v = bo2[r];
        } else {
            int rr = r - 40;
            if (k >= 40 && k < 80) v = Wt2[rr * 40 + (k - 40)];
            else if (k == 80) v = bt2[rr];
        }
        W2s[i] = f2bf(v);
    }
    for (int i = t0; i < 1536; i += NT) {
        int r = i / 96, k = i - r * 96;
        float v = 0.f;
        if (r < 9) {
            if (k < 40) v = Wo3[r * 40 + k];
            else if (k == 80) v = bo3[r];
        } else if (r < 12) {
            int rr = r - 9;
            if (k >= 40 && k < 80) v = Wt3[rr * 40 + (k - 40)];
            else if (k == 80) v = bt3[rr];
        }
        W3s[i] = f2bf(v);
    }
    for (int i = t0; i < 80; i += NT)
        b1s[i] = (i < 40) ? bo1[i] : bt1[i - 40];
}

// ---------------------------------------------------------------------------
// Main: one wave = 64 columns (4 tiles of 16). 1024 blocks = 4 blocks/CU =
// 4 waves/SIMD. launch_bounds(256,2) -> VGPR budget 128 (r5-proven, NO spill;
// r6's (256,4) clamped VGPR to 64 and spilled ~80MB). l3s stride 18 u16:
// bank = lane*9 mod 32, gcd(9,32)=1 -> per-column b128 reads 2-way (free);
// stride 16 was a 16-way conflict. hst stride 120 keeps 2-way.
// ---------------------------------------------------------------------------
__global__ __launch_bounds__(256, 2) void mlp_mfma(
    const float* __restrict__ x, const u16* __restrict__ ws,
    float* __restrict__ out)
{
    const u16* W1s = ws;
    const u16* W2s = ws + 5120;
    const u16* W3s = ws + 12800;
    const float* b1s = (const float*)(ws + 14336);

    __shared__ u16 hst[4][16][120];   // [wave][col][row(96 used)]
    __shared__ u16 l3s[4][64][18];    // [wave][col][row(16 used, pad 18)]

    const int tid = threadIdx.x;
    const int wid = tid >> 6;
    const int lane = tid & 63;
    const int g = lane >> 4;
    const int c = lane & 15;
    const int wgid = blockIdx.x * 4 + wid;   // 0..4095
    const int cbase = wgid * 64;

    // ---- A-fragments (weights) ----
    bf16x8 A1[5][2], A3[3];
    f32x4 b1v[5];
#pragma unroll
    for (int m = 0; m < 5; ++m) {
#pragma unroll
        for (int s = 0; s < 2; ++s)
            A1[m][s] = *(const bf16x8*)(W1s + (16 * m + c) * 64 + 32 * s + 8 * g);
        b1v[m] = *(const f32x4*)(b1s + 16 * m + 4 * g);
    }
    bf16x8 A2[5][3];
#pragma unroll
    for (int m = 0; m < 5; ++m)
#pragma unroll
        for (int s = 0; s < 3; ++s)
            if (!(s == 0 && m >= 3))
                A2[m][s] = *(const bf16x8*)(W2s + (16 * m + c) * 96 + 32 * s + 8 * g);
#pragma unroll
    for (int s = 0; s < 3; ++s)
        A3[s] = *(const bf16x8*)(W3s + c * 96 + 32 * s + 8 * g);

    // ---- hst pad rows 80..95: row 80 = 1.0 (bias row), rest 0 ----
    {
        uint2 z;
        z.x = (g == 0) ? 0x00003f80u : 0u;
        z.y = 0u;
        *(uint2*)&hst[wid][c][80 + 4 * g] = z;
    }

    // ---- per-lane x byte offsets (B-frag pattern) ----
    u32 xoff[16];
#pragma unroll
    for (int jj = 0; jj < 16; ++jj) {
        int row = 8 * g + (jj & 7) + 32 * (jj >> 3);
        xoff[jj] = (u32)((row * KC + cbase + c) * 4);
    }
    const char* xb_ = (const char*)x;

#pragma unroll
    for (int t = 0; t < 4; ++t) {
        float xr[16];
#pragma unroll
        for (int jj = 0; jj < 16; ++jj)
            xr[jj] = *(const float*)(xb_ + (xoff[jj] + t * 64));
        bf16x8 xv[2];
#pragma unroll
        for (int s = 0; s < 2; ++s) {
            union { u32 u[4]; bf16x8 v; } uu;
#pragma unroll
            for (int p = 0; p < 4; ++p)
                uu.u[p] = pk2(xr[8 * s + 2 * p], xr[8 * s + 2 * p + 1]);
            xv[s] = uu.v;
        }

        // ---- L1 ----
        f32x4 a1[5];
#pragma unroll
        for (int m = 0; m < 5; ++m) a1[m] = b1v[m];
#pragma unroll
        for (int s = 0; s < 2; ++s)
#pragma unroll
            for (int m = 0; m < 5; ++m)
                a1[m] = __builtin_amdgcn_mfma_f32_16x16x32_bf16(
                    A1[m][s], xv[s], a1[m], 0, 0, 0);
#pragma unroll
        for (int m = 0; m < 5; ++m) {
            uint2 w;
            w.x = pk2(fmaxf(a1[m][0], 0.f), fmaxf(a1[m][1], 0.f));
            w.y = pk2(fmaxf(a1[m][2], 0.f), fmaxf(a1[m][3], 0.f));
            *(uint2*)&hst[wid][c][16 * m + 4 * g] = w;
        }

        // ---- L2 (K=96; skip zero block-diag frags m>=3,s=0) ----
        f32x4 a2[5];
#pragma unroll
        for (int m = 0; m < 5; ++m) a2[m] = f32x4{0.f, 0.f, 0.f, 0.f};
#pragma unroll
        for (int s = 0; s < 3; ++s) {
            bf16x8 hb = *(const bf16x8*)&hst[wid][c][32 * s + 8 * g];
#pragma unroll
            for (int m = 0; m < 5; ++m)
                if (!(s == 0 && m >= 3))
                    a2[m] = __builtin_amdgcn_mfma_f32_16x16x32_bf16(
                        A2[m][s], hb, a2[m], 0, 0, 0);
        }
#pragma unroll
        for (int m = 0; m < 5; ++m) {
            uint2 w;
            w.x = pk2(fmaxf(a2[m][0], 0.f), fmaxf(a2[m][1], 0.f));
            w.y = pk2(fmaxf(a2[m][2], 0.f), fmaxf(a2[m][3], 0.f));
            *(uint2*)&hst[wid][c][16 * m + 4 * g] = w;
        }

        // ---- L3 ----
        f32x4 a3 = f32x4{0.f, 0.f, 0.f, 0.f};
#pragma unroll
        for (int s = 0; s < 3; ++s) {
            bf16x8 hb = *(const bf16x8*)&hst[wid][c][32 * s + 8 * g];
            a3 = __builtin_amdgcn_mfma_f32_16x16x32_bf16(
                A3[s], hb, a3, 0, 0, 0);
        }
        {
            uint2 w;
            w.x = pk2(fmaxf(a3[0], 0.f), fmaxf(a3[1], 0.f));
            w.y = pk2(fmaxf(a3[2], 0.f), fmaxf(a3[3], 0.f));
            *(uint2*)&l3s[wid][16 * t + c][4 * g] = w;
        }
    }

    // ---- per-column phase: lane <-> column cbase+lane ----
    {
        uint4 q0 = *(const uint4*)&l3s[wid][lane][0];
        uint2 q1 = *(const uint2*)&l3s[wid][lane][8];
        float om[9];
        om[0] = bf2f(q0.x & 0xffffu); om[1] = bf2f(q0.x >> 16);
        om[2] = bf2f(q0.y & 0xffffu); om[3] = bf2f(q0.y >> 16);
        om[4] = bf2f(q0.z & 0xffffu); om[5] = bf2f(q0.z >> 16);
        om[6] = bf2f(q0.w & 0xffffu); om[7] = bf2f(q0.w >> 16);
        om[8] = bf2f(q1.x & 0xffffu);
        float tr0 = bf2f(q1.x >> 16);
        float tr1 = bf2f(q1.y & 0xffffu);
        float tr2 = bf2f(q1.y >> 16);

        const size_t ob = (size_t)cbase + lane;
#pragma unroll
        for (int j = 0; j < 9; ++j)
            out[(size_t)j * KC + ob] = om[j];
        out[(size_t)18 * KC + ob] = tr0;
        out[(size_t)19 * KC + ob] = tr1;
        out[(size_t)20 * KC + ob] = tr2;

        // expm: scale 1/32, Taylor-9 Horner, 5 squarings
        float B[9];
#pragma unroll
        for (int i = 0; i < 9; ++i) B[i] = om[i] * (1.0f / 32.0f);
        float T[9] = {1.f, 0.f, 0.f, 0.f, 1.f, 0.f, 0.f, 0.f, 1.f};
#pragma unroll
        for (int m = 9; m >= 1; --m) {
            float U[9];
#pragma unroll
            for (int rr = 0; rr < 3; ++rr)
#pragma unroll
                for (int cc = 0; cc < 3; ++cc)
                    U[rr * 3 + cc] = B[rr * 3 + 0] * T[0 * 3 + cc]
                                   + B[rr * 3 + 1] * T[1 * 3 + cc]
                                   + B[rr * 3 + 2] * T[2 * 3 + cc];
            const float s = 1.0f / (float)m;
#pragma unroll
            for (int i = 0; i < 9; ++i)
                T[i] = U[i] * s + ((i == 0 || i == 4 || i == 8) ? 1.0f : 0.0f);
        }
#pragma unroll
        for (int q = 0; q < 5; ++q) {
            float U[9];
#pragma unroll
            for (int rr = 0; rr < 3; ++rr)
#pragma unroll
                for (int cc = 0; cc < 3; ++cc)
                    U[rr * 3 + cc] = T[rr * 3 + 0] * T[0 * 3 + cc]
                                   + T[rr * 3 + 1] * T[1 * 3 + cc]
                                   + T[rr * 3 + 2] * T[2 * 3 + cc];
#pragma unroll
            for (int i = 0; i < 9; ++i) T[i] = U[i];
        }
#pragma unroll
        for (int j = 0; j < 9; ++j)
            out[(size_t)(9 + j) * KC + ob] = T[j];
    }
}

extern "C" void kernel_launch(void* const* d_in, const int* in_sizes, int n_in,
                              void* d_out, int out_size, void* d_ws, size_t ws_size,
                              hipStream_t stream) {
    const float* x   = (const float*)d_in[0];
    const float* Wo1 = (const float*)d_in[1];
    const float* bo1 = (const float*)d_in[2];
    const float* Wo2 = (const float*)d_in[3];
    const float* bo2 = (const float*)d_in[4];
    const float* Wo3 = (const float*)d_in[5];
    const float* bo3 = (const float*)d_in[6];
    const float* Wt1 = (const float*)d_in[7];
    const float* bt1 = (const float*)d_in[8];
    const float* Wt2 = (const float*)d_in[9];
    const float* bt2 = (const float*)d_in[10];
    const float* Wt3 = (const float*)d_in[11];
    const float* bt3 = (const float*)d_in[12];

    u16* ws = (u16*)d_ws;
    float* out = (float*)d_out;

    hipLaunchKernelGGL(prep, dim3(16), dim3(256), 0, stream,
                       Wo1, bo1, Wo2, bo2, Wo3, bo3,
                       Wt1, bt1, Wt2, bt2, Wt3, bt3, ws);
    hipLaunchKernelGGL(mlp_mfma, dim3(1024), dim3(256), 0, stream,
                       x, ws, out);
}

// Round 8
// 33.591 us; speedup vs baseline: 1.5501x; 1.0243x over previous
//
#include <hip/hip_runtime.h>
#include <hip/hip_bf16.h>

#define KC 262144

typedef __attribute__((ext_vector_type(8))) short bf16x8;
typedef __attribute__((ext_vector_type(4))) float f32x4;
typedef unsigned short u16;
typedef unsigned int u32;

__device__ __forceinline__ u16 f2bf(float f) {
    u32 u = __float_as_uint(f);
    return (u16)((u + 0x7fffu + ((u >> 16) & 1u)) >> 16);   // RNE (prep only)
}
// main-kernel pack: compiler-native converts (fuse to v_cvt_pk_bf16_f32)
__device__ __forceinline__ u32 pk2(float a, float b) {
    u16 lo = __bfloat16_as_ushort(__float2bfloat16(a));
    u16 hi = __bfloat16_as_ushort(__float2bfloat16(b));
    return (u32)lo | ((u32)hi << 16);
}
__device__ __forceinline__ float bf2f(u32 h) {
    return __uint_as_float(h << 16);
}

// ---------------------------------------------------------------------------
// Prep: stacked bf16 weights in ws (bias via ones-row at k==80 for L2/L3).
//   W1s u16[80][64]   rows 0..39 = W_o1, 40..79 = W_t1
//   W2s u16[80][96]   block-diag W_o2/W_t2, col 80 = bias
//   W3s u16[16][96]   rows 0..8 = W_o3 | 9..11 = W_t3 (cols 40..79) | 12..15=0
//   b1s f32[80]       [b_o1 ; b_t1]
// ---------------------------------------------------------------------------
__global__ __launch_bounds__(256) void prep(
    const float* __restrict__ Wo1, const float* __restrict__ bo1,
    const float* __restrict__ Wo2, const float* __restrict__ bo2,
    const float* __restrict__ Wo3, const float* __restrict__ bo3,
    const float* __restrict__ Wt1, const float* __restrict__ bt1,
    const float* __restrict__ Wt2, const float* __restrict__ bt2,
    const float* __restrict__ Wt3, const float* __restrict__ bt3,
    u16* __restrict__ ws)
{
    u16* W1s = ws;                      // 5120 u16
    u16* W2s = ws + 5120;               // 7680 u16
    u16* W3s = ws + 12800;              // 1536 u16
    float* b1s = (float*)(ws + 14336);  // 80 f32
    const int t0 = blockIdx.x * 256 + threadIdx.x;
    const int NT = gridDim.x * 256;

    for (int i = t0; i < 5120; i += NT) {
        int r = i >> 6, k = i & 63;
        float v = (r < 40) ? Wo1[r * 64 + k] : Wt1[(r - 40) * 64 + k];
        W1s[i] = f2bf(v);
    }
    for (int i = t0; i < 7680; i += NT) {
        int r = i / 96, k = i - r * 96;
        float v = 0.f;
        if (r < 40) {
            if (k < 40) v = Wo2[r * 40 + k];
            else if (k == 80) v = bo2[r];
        } else {
            int rr = r - 40;
            if (k >= 40 && k < 80) v = Wt2[rr * 40 + (k - 40)];
            else if (k == 80) v = bt2[rr];
        }
        W2s[i] = f2bf(v);
    }
    for (int i = t0; i < 1536; i += NT) {
        int r = i / 96, k = i - r * 96;
        float v = 0.f;
        if (r < 9) {
            if (k < 40) v = Wo3[r * 40 + k];
            else if (k == 80) v = bo3[r];
        } else if (r < 12) {
            int rr = r - 9;
            if (k >= 40 && k < 80) v = Wt3[rr * 40 + (k - 40)];
            else if (k == 80) v = bt3[rr];
        }
        W3s[i] = f2bf(v);
    }
    for (int i = t0; i < 80; i += NT)
        b1s[i] = (i < 40) ? bo1[i] : bt1[i - 40];
}

// ---------------------------------------------------------------------------
// Main: one wave = 64 columns (4 tiles of 16). 1024 blocks, VGPR~128 ->
// 4 blocks/CU, 4 waves/SIMD. Changes vs r7: (1) next-tile x prefetch into
// separate regs (hides ~900cy HBM latency under tile compute), (2) native
// __float2bfloat16 packing (compiler cvt_pk, was 9-op bit-twiddle).
// ---------------------------------------------------------------------------
__global__ __launch_bounds__(256, 2) void mlp_mfma(
    const float* __restrict__ x, const u16* __restrict__ ws,
    float* __restrict__ out)
{
    const u16* W1s = ws;
    const u16* W2s = ws + 5120;
    const u16* W3s = ws + 12800;
    const float* b1s = (const float*)(ws + 14336);

    __shared__ u16 hst[4][16][120];   // [wave][col][row(96 used)]
    __shared__ u16 l3s[4][64][18];    // [wave][col][row(16 used, pad 18)]

    const int tid = threadIdx.x;
    const int wid = tid >> 6;
    const int lane = tid & 63;
    const int g = lane >> 4;
    const int c = lane & 15;
    const int wgid = blockIdx.x * 4 + wid;   // 0..4095
    const int cbase = wgid * 64;

    // ---- A-fragments (weights) ----
    bf16x8 A1[5][2], A3[3];
    f32x4 b1v[5];
#pragma unroll
    for (int m = 0; m < 5; ++m) {
#pragma unroll
        for (int s = 0; s < 2; ++s)
            A1[m][s] = *(const bf16x8*)(W1s + (16 * m + c) * 64 + 32 * s + 8 * g);
        b1v[m] = *(const f32x4*)(b1s + 16 * m + 4 * g);
    }
    bf16x8 A2[5][3];
#pragma unroll
    for (int m = 0; m < 5; ++m)
#pragma unroll
        for (int s = 0; s < 3; ++s)
            if (!(s == 0 && m >= 3))
                A2[m][s] = *(const bf16x8*)(W2s + (16 * m + c) * 96 + 32 * s + 8 * g);
#pragma unroll
    for (int s = 0; s < 3; ++s)
        A3[s] = *(const bf16x8*)(W3s + c * 96 + 32 * s + 8 * g);

    // ---- hst pad rows 80..95: row 80 = 1.0 (bias row), rest 0 ----
    {
        uint2 z;
        z.x = (g == 0) ? 0x00003f80u : 0u;
        z.y = 0u;
        *(uint2*)&hst[wid][c][80 + 4 * g] = z;
    }

    // ---- per-lane x byte offsets (B-frag pattern) ----
    u32 xoff[16];
#pragma unroll
    for (int jj = 0; jj < 16; ++jj) {
        int row = 8 * g + (jj & 7) + 32 * (jj >> 3);
        xoff[jj] = (u32)((row * KC + cbase + c) * 4);
    }
    const char* xb_ = (const char*)x;

    // ---- prologue: tile-0 x loads ----
    float xr[16];
#pragma unroll
    for (int jj = 0; jj < 16; ++jj)
        xr[jj] = *(const float*)(xb_ + xoff[jj]);

#pragma unroll
    for (int t = 0; t < 4; ++t) {
        // pack current tile (frees xr for reuse)
        bf16x8 xv[2];
#pragma unroll
        for (int s = 0; s < 2; ++s) {
            union { u32 u[4]; bf16x8 v; } uu;
#pragma unroll
            for (int p = 0; p < 4; ++p)
                uu.u[p] = pk2(xr[8 * s + 2 * p], xr[8 * s + 2 * p + 1]);
            xv[s] = uu.v;
        }

        // issue next tile's loads NOW; they fly during L1/L2/L3 compute
        float xrn[16];
        if (t < 3) {
#pragma unroll
            for (int jj = 0; jj < 16; ++jj)
                xrn[jj] = *(const float*)(xb_ + (xoff[jj] + (t + 1) * 64));
        }

        // ---- L1 ----
        f32x4 a1[5];
#pragma unroll
        for (int m = 0; m < 5; ++m) a1[m] = b1v[m];
#pragma unroll
        for (int s = 0; s < 2; ++s)
#pragma unroll
            for (int m = 0; m < 5; ++m)
                a1[m] = __builtin_amdgcn_mfma_f32_16x16x32_bf16(
                    A1[m][s], xv[s], a1[m], 0, 0, 0);
#pragma unroll
        for (int m = 0; m < 5; ++m) {
            uint2 w;
            w.x = pk2(fmaxf(a1[m][0], 0.f), fmaxf(a1[m][1], 0.f));
            w.y = pk2(fmaxf(a1[m][2], 0.f), fmaxf(a1[m][3], 0.f));
            *(uint2*)&hst[wid][c][16 * m + 4 * g] = w;
        }

        // ---- L2 (K=96; skip zero block-diag frags m>=3,s=0) ----
        f32x4 a2[5];
#pragma unroll
        for (int m = 0; m < 5; ++m) a2[m] = f32x4{0.f, 0.f, 0.f, 0.f};
#pragma unroll
        for (int s = 0; s < 3; ++s) {
            bf16x8 hb = *(const bf16x8*)&hst[wid][c][32 * s + 8 * g];
#pragma unroll
            for (int m = 0; m < 5; ++m)
                if (!(s == 0 && m >= 3))
                    a2[m] = __builtin_amdgcn_mfma_f32_16x16x32_bf16(
                        A2[m][s], hb, a2[m], 0, 0, 0);
        }
#pragma unroll
        for (int m = 0; m < 5; ++m) {
            uint2 w;
            w.x = pk2(fmaxf(a2[m][0], 0.f), fmaxf(a2[m][1], 0.f));
            w.y = pk2(fmaxf(a2[m][2], 0.f), fmaxf(a2[m][3], 0.f));
            *(uint2*)&hst[wid][c][16 * m + 4 * g] = w;
        }

        // ---- L3 ----
        f32x4 a3 = f32x4{0.f, 0.f, 0.f, 0.f};
#pragma unroll
        for (int s = 0; s < 3; ++s) {
            bf16x8 hb = *(const bf16x8*)&hst[wid][c][32 * s + 8 * g];
            a3 = __builtin_amdgcn_mfma_f32_16x16x32_bf16(
                A3[s], hb, a3, 0, 0, 0);
        }
        {
            uint2 w;
            w.x = pk2(fmaxf(a3[0], 0.f), fmaxf(a3[1], 0.f));
            w.y = pk2(fmaxf(a3[2], 0.f), fmaxf(a3[3], 0.f));
            *(uint2*)&l3s[wid][16 * t + c][4 * g] = w;
        }

        // rotate prefetched tile into xr
        if (t < 3) {
#pragma unroll
            for (int jj = 0; jj < 16; ++jj)
                xr[jj] = xrn[jj];
        }
    }

    // ---- per-column phase: lane <-> column cbase+lane ----
    {
        uint4 q0 = *(const uint4*)&l3s[wid][lane][0];
        uint2 q1 = *(const uint2*)&l3s[wid][lane][8];
        float om[9];
        om[0] = bf2f(q0.x & 0xffffu); om[1] = bf2f(q0.x >> 16);
        om[2] = bf2f(q0.y & 0xffffu); om[3] = bf2f(q0.y >> 16);
        om[4] = bf2f(q0.z & 0xffffu); om[5] = bf2f(q0.z >> 16);
        om[6] = bf2f(q0.w & 0xffffu); om[7] = bf2f(q0.w >> 16);
        om[8] = bf2f(q1.x & 0xffffu);
        float tr0 = bf2f(q1.x >> 16);
        float tr1 = bf2f(q1.y & 0xffffu);
        float tr2 = bf2f(q1.y >> 16);

        const size_t ob = (size_t)cbase + lane;
#pragma unroll
        for (int j = 0; j < 9; ++j)
            out[(size_t)j * KC + ob] = om[j];
        out[(size_t)18 * KC + ob] = tr0;
        out[(size_t)19 * KC + ob] = tr1;
        out[(size_t)20 * KC + ob] = tr2;

        // expm: scale 1/32, Taylor-9 Horner, 5 squarings
        float B[9];
#pragma unroll
        for (int i = 0; i < 9; ++i) B[i] = om[i] * (1.0f / 32.0f);
        float T[9] = {1.f, 0.f, 0.f, 0.f, 1.f, 0.f, 0.f, 0.f, 1.f};
#pragma unroll
        for (int m = 9; m >= 1; --m) {
            float U[9];
#pragma unroll
            for (int rr = 0; rr < 3; ++rr)
#pragma unroll
                for (int cc = 0; cc < 3; ++cc)
                    U[rr * 3 + cc] = B[rr * 3 + 0] * T[0 * 3 + cc]
                                   + B[rr * 3 + 1] * T[1 * 3 + cc]
                                   + B[rr * 3 + 2] * T[2 * 3 + cc];
            const float s = 1.0f / (float)m;
#pragma unroll
            for (int i = 0; i < 9; ++i)
                T[i] = U[i] * s + ((i == 0 || i == 4 || i == 8) ? 1.0f : 0.0f);
        }
#pragma unroll
        for (int q = 0; q < 5; ++q) {
            float U[9];
#pragma unroll
            for (int rr = 0; rr < 3; ++rr)
#pragma unroll
                for (int cc = 0; cc < 3; ++cc)
                    U[rr * 3 + cc] = T[rr * 3 + 0] * T[0 * 3 + cc]
                                   + T[rr * 3 + 1] * T[1 * 3 + cc]
                                   + T[rr * 3 + 2] * T[2 * 3 + cc];
#pragma unroll
            for (int i = 0; i < 9; ++i) T[i] = U[i];
        }
#pragma unroll
        for (int j = 0; j < 9; ++j)
            out[(size_t)(9 + j) * KC + ob] = T[j];
    }
}

extern "C" void kernel_launch(void* const* d_in, const int* in_sizes, int n_in,
                              void* d_out, int out_size, void* d_ws, size_t ws_size,
                              hipStream_t stream) {
    const float* x   = (const float*)d_in[0];
    const float* Wo1 = (const float*)d_in[1];
    const float* bo1 = (const float*)d_in[2];
    const float* Wo2 = (const float*)d_in[3];
    const float* bo2 = (const float*)d_in[4];
    const float* Wo3 = (const float*)d_in[5];
    const float* bo3 = (const float*)d_in[6];
    const float* Wt1 = (const float*)d_in[7];
    const float* bt1 = (const float*)d_in[8];
    const float* Wt2 = (const float*)d_in[9];
    const float* bt2 = (const float*)d_in[10];
    const float* Wt3 = (const float*)d_in[11];
    const float* bt3 = (const float*)d_in[12];

    u16* ws = (u16*)d_ws;
    float* out = (float*)d_out;

    hipLaunchKernelGGL(prep, dim3(16), dim3(256), 0, stream,
                       Wo1, bo1, Wo2, bo2, Wo3, bo3,
                       Wt1, bt1, Wt2, bt2, Wt3, bt3, ws);
    hipLaunchKernelGGL(mlp_mfma, dim3(1024), dim3(256), 0, stream,
                       x, ws, out);
}